// Round 4
// baseline (196.980 us; speedup 1.0000x reference)
//
#include <hip/hip_runtime.h>
#include <hip/hip_bf16.h>

// NVFP4 dynamic linear: x[2,2048,4096] f32, w[4096,4096] f32, bias[4096] -> out f32
// M=4096, N=4096, K=4096.
//
// amax -> quant/dequant to bf16 (exact: e2m1 code x e4m3 scale fits bf16;
// products accumulate exactly in fp32 MFMA) -> 256x256 bf16 MFMA GEMM.
// GEMM: ring-4 LDS (BK=32), 2 barriers/tile, register-prefetched fragments
// (next tile's ds_reads issued before current MFMA cluster so LDS serve
// hides under MFMA), counted vmcnt(6) once per tile. T1 XCD swizzle, T2 LDS
// swizzle, T5 setprio.
//
// ws: [0,8) amax bits | [256, +32MB) dx bf16 | [+32MB) dw bf16

typedef unsigned short u16;
typedef __bf16 bf16x8 __attribute__((ext_vector_type(8)));
typedef float f32x4 __attribute__((ext_vector_type(4)));
typedef unsigned short u16x8 __attribute__((ext_vector_type(8)));

#define GLD_LDS(gsrc, ldst)                                                     \
  __builtin_amdgcn_global_load_lds(                                             \
      (const __attribute__((address_space(1))) void*)(gsrc),                    \
      (__attribute__((address_space(3))) void*)(ldst), 16, 0, 0)

#define SBAR()                                                                  \
  do {                                                                          \
    asm volatile("" ::: "memory");                                              \
    __builtin_amdgcn_s_barrier();                                               \
    asm volatile("" ::: "memory");                                              \
  } while (0)

#define VMCNT_(N) asm volatile("s_waitcnt vmcnt(" #N ")" ::: "memory")
#define VMCNT(N) VMCNT_(N)

// ---------------- rounding helpers (bit-exact vs numpy RTNE) -----------------

__device__ __forceinline__ float round_e4m3(float v) {
  if (v < 0.015625f) {                        // subnormal grid, step 2^-9
    return rintf(v * 512.0f) * 0.001953125f;
  }
  unsigned b = __float_as_uint(v);
  unsigned e = (b >> 23) & 0xFFu;
  float step = __uint_as_float((e - 3u) << 23); // 2^(e-127-3)
  return rintf(v / step) * step;
}

__device__ __forceinline__ float round_e2m1(float v) {
  float a = fabsf(v);
  float step = (a < 2.0f) ? 0.5f : ((a < 4.0f) ? 1.0f : 2.0f);
  float q = fminf(rintf(a / step) * step, 6.0f);
  return copysignf(q, v);
}

// ---------------- kernel 1: global amax of |x| and |w| ----------------------

__global__ void nvfp4_amax_kernel(const float* __restrict__ x,
                                  const float* __restrict__ w,
                                  unsigned* __restrict__ sc, int nx4, int nw4) {
  const float4* src = blockIdx.y ? (const float4*)w : (const float4*)x;
  int n4 = blockIdx.y ? nw4 : nx4;
  float m = 0.f;
  for (int i = blockIdx.x * blockDim.x + threadIdx.x; i < n4;
       i += gridDim.x * blockDim.x) {
    float4 v = src[i];
    m = fmaxf(m, fmaxf(fmaxf(fabsf(v.x), fabsf(v.y)),
                       fmaxf(fabsf(v.z), fabsf(v.w))));
  }
#pragma unroll
  for (int off = 32; off; off >>= 1) m = fmaxf(m, __shfl_down(m, off));
  __shared__ float red[4];
  if ((threadIdx.x & 63) == 0) red[threadIdx.x >> 6] = m;
  __syncthreads();
  if (threadIdx.x == 0) {
    m = fmaxf(fmaxf(red[0], red[1]), fmaxf(red[2], red[3]));
    atomicMax(&sc[blockIdx.y], __float_as_uint(m));
  }
}

// ------------- kernel 2/3: quantize->dequantize to bf16 ---------------------

__global__ void nvfp4_quant_kernel(const float* __restrict__ src,
                                   u16* __restrict__ dst,
                                   const unsigned* __restrict__ sc, int which,
                                   int nblk) {
  int idx = blockIdx.x * blockDim.x + threadIdx.x;
  if (idx >= nblk) return;
  float amax = fmaxf(__uint_as_float(sc[which]), 1e-12f);
  float gs = 2688.0f / amax;

  float4 v[4];
  const float4* p = (const float4*)src + (size_t)idx * 4;
  v[0] = p[0]; v[1] = p[1]; v[2] = p[2]; v[3] = p[3];
  const float* fv = (const float*)v;

  float bamax = 0.f;
#pragma unroll
  for (int i = 0; i < 16; ++i) bamax = fmaxf(bamax, fabsf(fv[i]));

  float sf = round_e4m3((bamax * gs) / 6.0f);
  float sfs = fmaxf(sf, 1e-12f);
  float r = gs / sfs;

  u16 ob[16];
#pragma unroll
  for (int i = 0; i < 16; ++i) {
    float q = round_e2m1(fv[i] * r);
    float d = q * sf;                        // exact in bf16
    ob[i] = (u16)(__float_as_uint(d) >> 16);
  }
  u16x8* o = (u16x8*)(dst + (size_t)idx * 16);
  o[0] = *(u16x8*)ob;
  o[1] = *(u16x8*)(ob + 8);
}

// ---------------- kernel 4: 256x256 bf16 GEMM ------------------------------
// 512 threads = 8 waves (2M x 4N), per-wave 128x64 = acc[8][4]. BK=32,
// ring-4 LDS. Per tile t (steady state):
//   stage A(t+3); vmcnt(6); SBAR;
//   read aw(t,ih1); MFMA ih0 (16);            <- aw serve hides under MFMA
//   stage B(t+3); read av,bv(t+1); MFMA ih1;  <- t+1 serve hides under MFMA
//   SBAR;
// vmcnt(6): outstanding halves A(t+1),B(t+1),A(t+2),B(t+2),A(t+3) (2 loads
// each) -> allow youngest 6, require tile t+1 resident (read next).

#define BM 256
#define BN 256
#define BK 32
#define TILE_E 8192   /* 256*32 u16 elements per ring buffer */

__global__ __launch_bounds__(512, 2) void nvfp4_gemm_kernel(
    const u16* __restrict__ A,   // dx [M][K]
    const u16* __restrict__ B,   // dw [N][K]
    const float* __restrict__ bias, const unsigned* __restrict__ sc,
    float* __restrict__ C, int M, int N, int K) {
  __shared__ u16 lA[4][TILE_E];
  __shared__ u16 lB[4][TILE_E];
  const u16* lAflat = &lA[0][0];
  const u16* lBflat = &lB[0][0];

  const int tid = threadIdx.x;
  const int lane = tid & 63;
  const int wv = tid >> 6;
  const int wm = wv >> 2;        // 0..1
  const int wn = wv & 3;         // 0..3

  // T1: XCD-aware swizzle (256 blocks, 8 XCDs x 32; 4x8 tile region per XCD)
  const int bid = blockIdx.x;
  const int xcd = bid & 7, loc = bid >> 3;
  const int tm0 = ((xcd & 3) * 4 + (loc & 3)) * BM;
  const int tn0 = ((xcd >> 2) * 8 + (loc >> 2)) * BN;

  // ---- staging addressing (pre-swizzled global source, linear LDS dest) ----
  const int srow = tid >> 2;                 // 0..127
  const int skey = (srow >> 1) & 3;
  const int scol = ((tid & 3) ^ skey) * 8;   // swizzled 8-elem slot
  const u16* gA0 = A + (size_t)(tm0 + srow) * K + scol;
  const u16* gA1 = A + (size_t)(tm0 + 128 + srow) * K + scol;
  const u16* gB0 = B + (size_t)(tn0 + srow) * K + scol;
  const u16* gB1 = B + (size_t)(tn0 + 128 + srow) * K + scol;
  const int ld0 = tid * 8;
  const int ld1 = tid * 8 + 4096;

#define STAGE_A(tt)                                                             \
  do {                                                                          \
    int _o = ((tt) & 3) * TILE_E;                                               \
    GLD_LDS(gA0 + (size_t)(tt) * BK, lAflat + _o + ld0);                        \
    GLD_LDS(gA1 + (size_t)(tt) * BK, lAflat + _o + ld1);                        \
  } while (0)
#define STAGE_B(tt)                                                             \
  do {                                                                          \
    int _o = ((tt) & 3) * TILE_E;                                               \
    GLD_LDS(gB0 + (size_t)(tt) * BK, lBflat + _o + ld0);                        \
    GLD_LDS(gB1 + (size_t)(tt) * BK, lBflat + _o + ld1);                        \
  } while (0)

  // ---- fragment addressing (T2 swizzle on read side, same involution) ------
  const int rb = lane & 15;
  const int cc = (((lane >> 4) ^ ((rb >> 1) & 3)) << 3);
  const int aoff = (wm * 128 + rb) * BK + cc;  // ih0 rows; ih1 = +64*BK
  const int boff = (wn * 64 + rb) * BK + cc;

#define READ_AB(AV, BV, tt)                                                     \
  do {                                                                          \
    const u16* _ba = lAflat + ((tt) & 3) * TILE_E;                              \
    const u16* _bb = lBflat + ((tt) & 3) * TILE_E;                              \
    AV[0] = *(const bf16x8*)(_ba + aoff);                                       \
    AV[1] = *(const bf16x8*)(_ba + aoff + 512);                                 \
    AV[2] = *(const bf16x8*)(_ba + aoff + 1024);                                \
    AV[3] = *(const bf16x8*)(_ba + aoff + 1536);                                \
    BV[0] = *(const bf16x8*)(_bb + boff);                                       \
    BV[1] = *(const bf16x8*)(_bb + boff + 512);                                 \
    BV[2] = *(const bf16x8*)(_bb + boff + 1024);                                \
    BV[3] = *(const bf16x8*)(_bb + boff + 1536);                                \
  } while (0)

#define READ_AW(AW, tt)                                                         \
  do {                                                                          \
    const u16* _ba = lAflat + ((tt) & 3) * TILE_E + 2048; /* +64 rows */        \
    AW[0] = *(const bf16x8*)(_ba + aoff);                                       \
    AW[1] = *(const bf16x8*)(_ba + aoff + 512);                                 \
    AW[2] = *(const bf16x8*)(_ba + aoff + 1024);                                \
    AW[3] = *(const bf16x8*)(_ba + aoff + 1536);                                \
  } while (0)

#define MFMA_IH0(AV, BV)                                                        \
  do {                                                                          \
    _Pragma("unroll") for (int _i = 0; _i < 4; ++_i)                            \
        _Pragma("unroll") for (int _j = 0; _j < 4; ++_j)                        \
            acc[_i][_j] = __builtin_amdgcn_mfma_f32_16x16x32_bf16(              \
                AV[_i], BV[_j], acc[_i][_j], 0, 0, 0);                          \
  } while (0)

#define MFMA_IH1(AW, BV)                                                        \
  do {                                                                          \
    _Pragma("unroll") for (int _i = 0; _i < 4; ++_i)                            \
        _Pragma("unroll") for (int _j = 0; _j < 4; ++_j)                        \
            acc[4 + _i][_j] = __builtin_amdgcn_mfma_f32_16x16x32_bf16(          \
                AW[_i], BV[_j], acc[4 + _i][_j], 0, 0, 0);                      \
  } while (0)

  // One tile step. CAV/CBV hold tile t's ih0-A and B frags (read earlier).
  // CAW: scratch for t's ih1-A frags. NAV/NBV: next tile's frags (read here).
#define TILE_STEP(CAV, CBV, CAW, NAV, NBV, t, VM, STA, STB, RDN)                \
  do {                                                                          \
    if (STA) STAGE_A((t) + 3);                                                  \
    VMCNT(VM);                                                                  \
    SBAR();                                                                     \
    READ_AW(CAW, t);                                                            \
    __builtin_amdgcn_s_setprio(1);                                              \
    MFMA_IH0(CAV, CBV);                                                         \
    __builtin_amdgcn_s_setprio(0);                                              \
    if (STB) STAGE_B((t) + 3);                                                  \
    if (RDN) READ_AB(NAV, NBV, (t) + 1);                                        \
    __builtin_amdgcn_s_setprio(1);                                              \
    MFMA_IH1(CAW, CBV);                                                         \
    __builtin_amdgcn_s_setprio(0);                                              \
    SBAR();                                                                     \
  } while (0)

  f32x4 acc[8][4] = {};
  bf16x8 xav[4], xbv[4], xaw[4], yav[4], ybv[4], yaw[4];

  // prologue: stage A/B for tiles 0,1,2 -> vmcnt(4) leaves {A1,B1,A2,B2}
  STAGE_A(0); STAGE_B(0);
  STAGE_A(1); STAGE_B(1);
  STAGE_A(2); STAGE_B(2);
  VMCNT(4);
  SBAR();
  READ_AB(xav, xbv, 0);

  // main: tiles 0..123 as 62 X/Y pairs, then 124..127 tail (NT = K/BK = 128)
  for (int p = 0; p < 62; ++p) {
    const int t0 = 2 * p;
    TILE_STEP(xav, xbv, xaw, yav, ybv, t0,     6, 1, 1, 1);
    TILE_STEP(yav, ybv, yaw, xav, xbv, t0 + 1, 6, 1, 1, 1);
  }
  TILE_STEP(xav, xbv, xaw, yav, ybv, 124, 6, 1, 1, 1);
  TILE_STEP(yav, ybv, yaw, xav, xbv, 125, 4, 0, 0, 1);
  TILE_STEP(xav, xbv, xaw, yav, ybv, 126, 0, 0, 0, 1);
  TILE_STEP(yav, ybv, yaw, xav, xbv, 127, 0, 0, 0, 0);

  // ---------------- epilogue: out = alpha*acc + bias ------------------------
  float ax = fmaxf(__uint_as_float(sc[0]), 1e-12f);
  float aw_ = fmaxf(__uint_as_float(sc[1]), 1e-12f);
  float alpha = (ax * aw_) / 7225344.0f;     // amax_x*amax_w / 2688^2

  const int orow = (lane >> 4) * 4;          // C/D: col=lane&15, row=(lane>>4)*4+reg
  const int ocol = lane & 15;
#pragma unroll
  for (int ai = 0; ai < 8; ++ai) {
#pragma unroll
    for (int j = 0; j < 4; ++j) {
      int col = tn0 + wn * 64 + j * 16 + ocol;
      float bvv = bias[col];
#pragma unroll
      for (int rr = 0; rr < 4; ++rr) {
        int row = tm0 + wm * 128 + ai * 16 + orow + rr;
        C[(size_t)row * N + col] = alpha * acc[ai][j][rr] + bvv;
      }
    }
  }
#undef STAGE_A
#undef STAGE_B
#undef READ_AB
#undef READ_AW
#undef MFMA_IH0
#undef MFMA_IH1
#undef TILE_STEP
}

// ---------------------------------------------------------------------------

extern "C" void kernel_launch(void* const* d_in, const int* in_sizes, int n_in,
                              void* d_out, int out_size, void* d_ws, size_t ws_size,
                              hipStream_t stream) {
  const float* x = (const float*)d_in[0];
  const float* w = (const float*)d_in[1];
  const float* bias = (const float*)d_in[2];
  float* out = (float*)d_out;

  const int N = in_sizes[2];
  const int K = in_sizes[1] / N;
  const int M = in_sizes[0] / K;

  unsigned char* ws = (unsigned char*)d_ws;
  unsigned* sc = (unsigned*)ws;
  u16* dx = (u16*)(ws + 256);
  u16* dw = (u16*)(ws + 256 + (size_t)M * K * sizeof(u16));

  hipMemsetAsync(sc, 0, 8, stream);

  nvfp4_amax_kernel<<<dim3(256, 2), 256, 0, stream>>>(x, w, sc, M * K / 4,
                                                      N * K / 4);

  int nbx = M * K / 16, nbw = N * K / 16;
  nvfp4_quant_kernel<<<(nbx + 255) / 256, 256, 0, stream>>>(x, dx, sc, 0, nbx);
  nvfp4_quant_kernel<<<(nbw + 255) / 256, 256, 0, stream>>>(w, dw, sc, 1, nbw);

  nvfp4_gemm_kernel<<<dim3((M / BM) * (N / BN)), 512, 0, stream>>>(
      dx, dw, bias, sc, out, M, N, K);
}